// Round 6
// baseline (354.776 us; speedup 1.0000x reference)
//
#include <hip/hip_runtime.h>
#include <hip/hip_fp16.h>

typedef unsigned int uint32;

#define B_ 16
#define N_ 400
#define D_ 256
#define H_ 8
#define DH_ 32
#define NW_ 4

#if __has_builtin(__builtin_amdgcn_exp2f)
#define EXP2(x) __builtin_amdgcn_exp2f(x)
#else
#define EXP2(x) exp2f(x)
#endif

// log2(e)/sqrt(32): exp(|qk/sqrt(32) * w|) == exp2(|qk*SCL * w|)
#define QK_SCL 0.2550348f

using bf16x8 = __attribute__((ext_vector_type(8))) short;
using f16x8  = __attribute__((ext_vector_type(8))) _Float16;
using f32x4  = __attribute__((ext_vector_type(4))) float;

__device__ __forceinline__ ushort f2b(float f) {
  uint32 u = __float_as_uint(f);
  uint32 r = (u + 0x7fffu + ((u >> 16) & 1u)) >> 16;
  return (ushort)r;
}
__device__ __forceinline__ float b2f(ushort u) {
  return __uint_as_float(((uint32)u) << 16);
}
__device__ __forceinline__ void unpack2(uint32 u, float* o) {
  o[0] = __uint_as_float(u << 16);
  o[1] = __uint_as_float(u & 0xffff0000u);
}
// pack high halves of two fp32 (truncating bf16): one v_perm
__device__ __forceinline__ uint32 packbf(float a, float b) {
  return __builtin_amdgcn_perm(__float_as_uint(b), __float_as_uint(a),
                               0x07060302u);
}

// ---------------------------------------------------------------------------
// Convert fp32 -> bf16. x, Wq/Wk/Wv flat; Wo/W1/W2 packed fragment-major:
// packed[((tile*(K/32)+ks)*16 + (n&15))*32 + (k&31)], tile=n>>4 — so a
// 16-row x 32-col MFMA B-fragment is 1 KB contiguous.
// ---------------------------------------------------------------------------
__global__ __launch_bounds__(256) void convert_kernel(
    const float* __restrict__ x,  const float* __restrict__ wq,
    const float* __restrict__ wk, const float* __restrict__ wv,
    const float* __restrict__ wo, const float* __restrict__ w1,
    const float* __restrict__ w2,
    ushort* __restrict__ xb,  ushort* __restrict__ wqb,
    ushort* __restrict__ wkb, ushort* __restrict__ wvb,
    ushort* __restrict__ wob, ushort* __restrict__ w1b,
    ushort* __restrict__ w2b) {
  int gid = blockIdx.x * 256 + threadIdx.x;   // unit = 4 floats
  const float* src; ushort* dst; int didx;
  if (gid < 409600) { src = x; dst = xb; didx = gid * 4; }
  else if ((gid -= 409600) < 16384) { src = wq; dst = wqb; didx = gid * 4; }
  else if ((gid -= 16384) < 16384)  { src = wk; dst = wkb; didx = gid * 4; }
  else if ((gid -= 16384) < 16384)  { src = wv; dst = wvb; didx = gid * 4; }
  else if ((gid -= 16384) < 16384) {  // Wo 256x256 packed
    int n = gid >> 6, kc = (gid & 63) * 4;
    src = wo; dst = wob;
    didx = (((n >> 4) * 8 + (kc >> 5)) << 9) + ((n & 15) << 5) + (kc & 31);
  } else if ((gid -= 16384) < 65536) {  // W1 1024x256 packed
    int n = gid >> 6, kc = (gid & 63) * 4;
    src = w1; dst = w1b;
    didx = (((n >> 4) * 8 + (kc >> 5)) << 9) + ((n & 15) << 5) + (kc & 31);
  } else {  // W2 256x1024 packed
    gid -= 65536;
    int n = gid >> 8, kc = (gid & 255) * 4;
    src = w2; dst = w2b;
    didx = (((n >> 4) * 32 + (kc >> 5)) << 9) + ((n & 15) << 5) + (kc & 31);
  }
  float4 f = ((const float4*)src)[gid];
  ushort4 u;
  u.x = f2b(f.x); u.y = f2b(f.y); u.z = f2b(f.z); u.w = f2b(f.w);
  *(ushort4*)&dst[didx] = u;
}

// ---------------------------------------------------------------------------
// Fused QKV GEMM (unchanged from round 3/4).
// q -> fp16 [b][h][m][32] * QK_SCL;  k -> fp16 [b][h][m][32];
// v -> fp16 transposed vt[b][d][m].
// ---------------------------------------------------------------------------
__global__ __launch_bounds__(256) void qkv_gemm(
    const ushort* __restrict__ xb, const ushort* __restrict__ wq,
    const ushort* __restrict__ wk, const ushort* __restrict__ wv,
    const float* __restrict__ bq, const float* __restrict__ bk,
    const float* __restrict__ bv,
    _Float16* __restrict__ qh, _Float16* __restrict__ kh,
    _Float16* __restrict__ vt) {
  __shared__ __align__(16) ushort As[2][64 * 40];
  __shared__ __align__(16) ushort Ws[2][64 * 40];
  int z = blockIdx.z;
  const ushort* W = (z == 0) ? wq : (z == 1) ? wk : wv;
  const float* bias = (z == 0) ? bq : (z == 1) ? bk : bv;

  int t = threadIdx.x;
  int l = t & 63, w = t >> 6;
  int n0 = blockIdx.x * 64, m0 = blockIdx.y * 64;
  int srow = t >> 2, sc = (t & 3) * 8;
  int lrow = l & 15, lk = (l >> 4) * 8;

  const uint4* ag = (const uint4*)&xb[(size_t)(m0 + srow) * 256 + sc];
  const uint4* wg = (const uint4*)&W[(size_t)(n0 + srow) * 256 + sc];
  uint4 ar = ag[0], wr = wg[0];

  f32x4 acc[4];
#pragma unroll
  for (int nt = 0; nt < 4; nt++) acc[nt] = {0.f, 0.f, 0.f, 0.f};

  for (int kk = 0; kk < 8; kk++) {
    int cur = kk & 1;
    *(uint4*)&As[cur][srow * 40 + sc] = ar;
    *(uint4*)&Ws[cur][srow * 40 + sc] = wr;
    if (kk + 1 < 8) { ar = ag[(kk + 1) * 4]; wr = wg[(kk + 1) * 4]; }
    __syncthreads();
    bf16x8 af = *(const bf16x8*)&As[cur][(16 * w + lrow) * 40 + lk];
#pragma unroll
    for (int nt = 0; nt < 4; nt++) {
      bf16x8 bf = *(const bf16x8*)&Ws[cur][(nt * 16 + lrow) * 40 + lk];
      acc[nt] = __builtin_amdgcn_mfma_f32_16x16x32_bf16(af, bf, acc[nt], 0, 0, 0);
    }
  }

  int mb = m0 + 16 * w + (l >> 4) * 4;  // multiple of 4 -> never crosses b*400
  int bb = mb / 400;
  int mi = mb - bb * 400;
#pragma unroll
  for (int nt = 0; nt < 4; nt++) {
    int n = n0 + nt * 16 + lrow;
    float bvv = bias[n];
    if (z < 2) {
      _Float16* out = z ? kh : qh;
      float scl = z ? 1.f : QK_SCL;
      int hh = n >> 5, dd = n & 31;
      _Float16* dst = out + (((size_t)(bb * 8 + hh)) * 400 + mi) * 32 + dd;
#pragma unroll
      for (int r = 0; r < 4; r++)
        dst[(size_t)r * 32] = (_Float16)((acc[nt][r] + bvv) * scl);
    } else {
      _Float16 h4[4];
#pragma unroll
      for (int r = 0; r < 4; r++) h4[r] = (_Float16)(acc[nt][r] + bvv);
      *(uint2*)&vt[((size_t)bb * 256 + n) * 400 + mi] = *(uint2*)h4;
    }
  }
}

// ---------------------------------------------------------------------------
// Fused attention v4: block = (b, head, 16 q-rows). Grid 3200.
//   P1: S[16][400] = (Q*scl)@K^T via MFMA -> LDS fp16 (pitch 424)
//   P2: 4 i-passes; 16 lanes per (i,n) row read aw CONTIGUOUS (256 B/instr);
//       s~ = copysign(exp2|S*w|, S*w) -> LDS bf16 (range-safe); z accumulated.
//   P3a: sc = sum_i s~_i * zinv_i -> scores (nontemporal) + fp16 into S
//   P3b: O = S @ V via MFMA on pre-transposed vt; cross-wave LDS reduce
// LDS: S 13568 + st 51200 + zin 256 = 65024 B  (2 blocks/CU)
// ---------------------------------------------------------------------------
#define SPV 424  // S pitch in halves: 848 B, 16B-aligned, 212 dw -> 2-way banks
#define STP 400  // st pitch in halves (contiguous rows)

__global__ __launch_bounds__(256) void attn_kernel(
    const _Float16* __restrict__ qh, const _Float16* __restrict__ kh,
    const _Float16* __restrict__ vt, const float* __restrict__ aw,
    float* __restrict__ scores, ushort* __restrict__ attnb) {
  __shared__ __align__(16) __half S[16 * SPV];
  __shared__ __align__(16) ushort st[4][16 * STP];
  __shared__ float zin[64];

  int id = blockIdx.x;
  int c = ((id >> 6) << 3) | (id & 7);  // 0..399: (b, n-tile); id%8 = XCD key
  int hh = (id >> 3) & 7;
  int b = c / 25;
  int n0 = (c - b * 25) * 16;

  int t = threadIdx.x;
  int w = t >> 6, l = t & 63;
  int lq = l >> 4, lr = l & 15;

  // ---- P1: S = (Q*scl) @ K^T ----
  {
    const _Float16* qbase = qh + (((size_t)(b * 8 + hh)) * 400 + n0) * 32;
    const _Float16* kbase = kh + ((size_t)(b * 8 + hh)) * 400 * 32;
    f16x8 af = *(const f16x8*)(qbase + lr * 32 + lq * 8);
    for (int mt = w; mt < 25; mt += 4) {
      f16x8 bf = *(const f16x8*)(kbase + (size_t)(mt * 16 + lr) * 32 + lq * 8);
      f32x4 cc = {0.f, 0.f, 0.f, 0.f};
      cc = __builtin_amdgcn_mfma_f32_16x16x32_f16(af, bf, cc, 0, 0, 0);
#pragma unroll
      for (int r = 0; r < 4; r++)
        S[(lq * 4 + r) * SPV + mt * 16 + lr] = __float2half(cc[r]);
    }
  }
  __syncthreads();

  // ---- P2: 4 i-passes; contiguous aw reads; s~ -> LDS; Z reduce ----
  {
    int n = t >> 4, p = t & 15;
    const __half* srow = S + n * SPV;
#pragma unroll
    for (int i = 0; i < 4; i++) {
      const float* wrow = aw + (((size_t)(b * 4 + i)) * 400 + n0 + n) * 400;
      ushort* srt = &st[i][n * STP];
      float z = 0.f;
      for (int m = p * 4; m < 400; m += 64) {
        float4 wv = *(const float4*)(wrow + m);
        uint2 sv = *(const uint2*)(srow + m);
        float2 f0 = __half22float2(*(const __half2*)&sv.x);
        float2 f1 = __half22float2(*(const __half2*)&sv.y);
        float t0 = f0.x * wv.x, t1 = f0.y * wv.y;
        float t2 = f1.x * wv.z, t3 = f1.y * wv.w;
        float e0 = EXP2(fabsf(t0)), e1 = EXP2(fabsf(t1));
        float e2 = EXP2(fabsf(t2)), e3 = EXP2(fabsf(t3));
        z += (e0 + e1) + (e2 + e3);
        uint2 pk;
        pk.x = packbf(copysignf(e0, t0), copysignf(e1, t1));
        pk.y = packbf(copysignf(e2, t2), copysignf(e3, t3));
        *(uint2*)(srt + m) = pk;
      }
      z += __shfl_xor(z, 1);
      z += __shfl_xor(z, 2);
      z += __shfl_xor(z, 4);
      z += __shfl_xor(z, 8);
      if (p == 0) zin[i * 16 + n] = 0.25f / (z + 1e-10f);  // folds /NW
    }
  }
  __syncthreads();

  // ---- P3a: combine; scores -> global (NT) + fp16 scores into S ----
  {
    int n = t >> 4, p = t & 15;
    float z0 = zin[n], z1 = zin[16 + n], z2 = zin[32 + n], z3 = zin[48 + n];
    __half* srow = S + n * SPV;
    const ushort* s0 = &st[0][n * STP];
    const ushort* s1 = &st[1][n * STP];
    const ushort* s2 = &st[2][n * STP];
    const ushort* s3 = &st[3][n * STP];
    float* scout = scores + (((size_t)(b * 8 + hh)) * 400 + n0 + n) * 400;
    for (int m = p * 4; m < 424; m += 64) {
      if (m < 400) {
        uint2 a0 = *(const uint2*)(s0 + m);
        uint2 a1 = *(const uint2*)(s1 + m);
        uint2 a2 = *(const uint2*)(s2 + m);
        uint2 a3 = *(const uint2*)(s3 + m);
        float v0[4], v1[4], v2[4], v3[4];
        unpack2(a0.x, &v0[0]); unpack2(a0.y, &v0[2]);
        unpack2(a1.x, &v1[0]); unpack2(a1.y, &v1[2]);
        unpack2(a2.x, &v2[0]); unpack2(a2.y, &v2[2]);
        unpack2(a3.x, &v3[0]); unpack2(a3.y, &v3[2]);
        f32x4 o;
#pragma unroll
        for (int j = 0; j < 4; j++) {
          float s = v0[j] * z0;
          s = fmaf(v1[j], z1, s);
          s = fmaf(v2[j], z2, s);
          s = fmaf(v3[j], z3, s);
          o[j] = s;
        }
        __builtin_nontemporal_store(o, (f32x4*)(scout + m));
        __half h4[4] = {__float2half(o[0]), __float2half(o[1]),
                        __float2half(o[2]), __float2half(o[3])};
        *(uint2*)(srow + m) = *(uint2*)h4;
      } else {
        uint2 zero = {0u, 0u};
        *(uint2*)(srow + m) = zero;  // zero-pad cols 400..423 for PV chunks
      }
    }
  }
  __syncthreads();

  // ---- P3b: O = S @ V (13 chunks of 32 m, split across waves) ----
  const _Float16* vbase = vt + (((size_t)b) * 256 + hh * 32) * 400;
  f32x4 a0 = {0.f, 0.f, 0.f, 0.f}, a1 = {0.f, 0.f, 0.f, 0.f};
  const _Float16* Sh = (const _Float16*)S;
  for (int c2 = w; c2 < 13; c2 += 4) {
    f16x8 sf = *(const f16x8*)(Sh + lr * SPV + c2 * 32 + lq * 8);
    f16x8 v0 = *(const f16x8*)(vbase + (size_t)lr * 400 + c2 * 32 + lq * 8);
    f16x8 v1 = *(const f16x8*)(vbase + (size_t)(16 + lr) * 400 + c2 * 32 + lq * 8);
    a0 = __builtin_amdgcn_mfma_f32_16x16x32_f16(sf, v0, a0, 0, 0, 0);
    a1 = __builtin_amdgcn_mfma_f32_16x16x32_f16(sf, v1, a1, 0, 0, 0);
  }
  __syncthreads();  // all S reads done before reusing st as float scratch
  float* Of = (float*)st;  // [4w][16n][32d] = 8192 B
#pragma unroll
  for (int r = 0; r < 4; r++) {
    Of[(w * 16 + lq * 4 + r) * 32 + lr] = a0[r];
    Of[(w * 16 + lq * 4 + r) * 32 + 16 + lr] = a1[r];
  }
  __syncthreads();
  for (int o = t; o < 512; o += 256) {
    int n = o >> 5, d = o & 31;
    float s = Of[n * 32 + d] + Of[512 + n * 32 + d] +
              Of[1024 + n * 32 + d] + Of[1536 + n * 32 + d];
    attnb[((size_t)(b * 400 + n0 + n)) * 256 + hh * 32 + d] = f2b(s);
  }
}

// ---------------------------------------------------------------------------
// Fused tail v2: 256 threads, 16 rows/block. Weights PACKED fragment-major ->
// every B-fragment load is one contiguous 1 KB wave read from L2.
// LDS: bufA 16x280 (8960) + relu 16x1048 (33536) + ln 512 = 43008 B (3 blk/CU)
// ---------------------------------------------------------------------------
#define HP 280   // bufA pitch halves: 560 B (16B-aligned, 140 dw -> 2-way)
#define RP 1048  // relu pitch halves: 2096 B (16B-aligned, 524 dw -> 2-way)

__global__ __launch_bounds__(256) void tail_kernel(
    const ushort* __restrict__ attnb, const ushort* __restrict__ wob,
    const float* __restrict__ bo, const float* __restrict__ x,
    const float* __restrict__ g1, const float* __restrict__ be1,
    const ushort* __restrict__ w1b, const float* __restrict__ b1,
    const ushort* __restrict__ w2b, const float* __restrict__ b2,
    const float* __restrict__ g2, const float* __restrict__ be2,
    float* __restrict__ yout) {
  __shared__ __align__(16) ushort bufA[16 * HP];
  __shared__ __align__(16) ushort relu[16 * RP];
  __shared__ float lnS[64], lnQ[64];

  int m0 = blockIdx.x * 16;
  int t = threadIdx.x, w = t >> 6, l = t & 63;
  int lr = l & 15, lq = l >> 4, row4 = lq * 4;

  // load 16 attn rows (bf16) into LDS
  {
    int row = t >> 4, c0 = (t & 15) * 16;
    *(uint4*)&bufA[row * HP + c0] =
        *(const uint4*)&attnb[(size_t)(m0 + row) * 256 + c0];
    *(uint4*)&bufA[row * HP + c0 + 8] =
        *(const uint4*)&attnb[(size_t)(m0 + row) * 256 + c0 + 8];
  }
  __syncthreads();

  // ---- Wo: 4 n-tiles per wave ----
  f32x4 acc[4];
#pragma unroll
  for (int nt = 0; nt < 4; nt++) acc[nt] = {0.f, 0.f, 0.f, 0.f};
  for (int ks = 0; ks < 8; ks++) {
    bf16x8 af = *(const bf16x8*)&bufA[lr * HP + ks * 32 + lq * 8];
#pragma unroll
    for (int nt = 0; nt < 4; nt++) {
      int tile = w * 4 + nt;
      bf16x8 bf = *(const bf16x8*)&wob[((tile * 8 + ks) << 9) + lr * 32 + lq * 8];
      acc[nt] = __builtin_amdgcn_mfma_f32_16x16x32_bf16(af, bf, acc[nt], 0, 0, 0);
    }
  }
  // epilogue: + bo + x resid; LN1 partials (per-row over nt + 16 lanes)
  float vals[4][4];
  float rs[4] = {0.f, 0.f, 0.f, 0.f}, rq[4] = {0.f, 0.f, 0.f, 0.f};
#pragma unroll
  for (int nt = 0; nt < 4; nt++) {
    int n = (w * 4 + nt) * 16 + lr;
    float bon = bo[n];
#pragma unroll
    for (int r = 0; r < 4; r++) {
      float v = acc[nt][r] + bon + x[(size_t)(m0 + row4 + r) * 256 + n];
      vals[nt][r] = v;
      rs[r] += v; rq[r] += v * v;
    }
  }
#pragma unroll
  for (int r = 0; r < 4; r++) {
#pragma unroll
    for (int o = 1; o < 16; o <<= 1) {
      rs[r] += __shfl_xor(rs[r], o);
      rq[r] += __shfl_xor(rq[r], o);
    }
  }
  if (lr == 0) {
#pragma unroll
    for (int r = 0; r < 4; r++) {
      lnS[(row4 + r) * 4 + w] = rs[r];
      lnQ[(row4 + r) * 4 + w] = rq[r];
    }
  }
  __syncthreads();
  {
    float mean[4], rsig[4];
#pragma unroll
    for (int r = 0; r < 4; r++) {
      int m = row4 + r;
      float s = lnS[m * 4] + lnS[m * 4 + 1] + lnS[m * 4 + 2] + lnS[m * 4 + 3];
      float q = lnQ[m * 4] + lnQ[m * 4 + 1] + lnQ[m * 4 + 2] + lnQ[m * 4 + 3];
      float mu = s * (1.f / 256.f);
      float va = q * (1.f / 256.f) - mu * mu;
      mean[r] = mu; rsig[r] = rsqrtf(va + 1e-5f);
    }
#pragma unroll
    for (int nt = 0; nt < 4; nt++) {
      int n = (w * 4 + nt) * 16 + lr;
      float g = g1[n], be = be1[n];
#pragma unroll
      for (int r = 0; r < 4; r++) {
        float h = (vals[nt][r] - mean[r]) * rsig[r] * g + be;
        bufA[(row4 + r) * HP + n] = f2b(h);
      }
    }
  }
  __syncthreads();

  // ---- FFN1: 16 n-tiles per wave, relu -> LDS ----
  {
    f32x4 a1[16];
#pragma unroll
    for (int nt = 0; nt < 16; nt++) a1[nt] = {0.f, 0.f, 0.f, 0.f};
    for (int ks = 0; ks < 8; ks++) {
      bf16x8 af = *(const bf16x8*)&bufA[lr * HP + ks * 32 + lq * 8];
#pragma unroll
      for (int nt = 0; nt < 16; nt++) {
        int tile = w * 16 + nt;
        bf16x8 bf = *(const bf16x8*)&w1b[((tile * 8 + ks) << 9) + lr * 32 + lq * 8];
        a1[nt] = __builtin_amdgcn_mfma_f32_16x16x32_bf16(af, bf, a1[nt], 0, 0, 0);
      }
    }
#pragma unroll
    for (int nt = 0; nt < 16; nt++) {
      int n = (w * 16 + nt) * 16 + lr;
      float bn = b1[n];
#pragma unroll
      for (int r = 0; r < 4; r++) {
        float v = fmaxf(a1[nt][r] + bn, 0.f);
        relu[(row4 + r) * RP + n] = f2b(v);
      }
    }
  }
  __syncthreads();

  // ---- FFN2: 4 n-tiles per wave, K=1024 from relu LDS ----
  f32x4 a2[4];
#pragma unroll
  for (int nt = 0; nt < 4; nt++) a2[nt] = {0.f, 0.f, 0.f, 0.f};
  for (int ks = 0; ks < 32; ks++) {
    bf16x8 af = *(const bf16x8*)&relu[lr * RP + ks * 32 + lq * 8];
#pragma unroll
    for (int nt = 0; nt < 4; nt++) {
      int tile = w * 4 + nt;
      bf16x8 bf = *(const bf16x8*)&w2b[((tile * 32 + ks) << 9) + lr * 32 + lq * 8];
      a2[nt] = __builtin_amdgcn_mfma_f32_16x16x32_bf16(af, bf, a2[nt], 0, 0, 0);
    }
  }
  // epilogue: + b2 + h resid; LN2
  float vals2[4][4];
  float rs2[4] = {0.f, 0.f, 0.f, 0.f}, rq2[4] = {0.f, 0.f, 0.f, 0.f};
#pragma unroll
  for (int nt = 0; nt < 4; nt++) {
    int n = (w * 4 + nt) * 16 + lr;
    float bn = b2[n];
#pragma unroll
    for (int r = 0; r < 4; r++) {
      float v = a2[nt][r] + bn + b2f(bufA[(row4 + r) * HP + n]);
      vals2[nt][r] = v;
      rs2[r] += v; rq2[r] += v * v;
    }
  }
#pragma unroll
  for (int r = 0; r < 4; r++) {
#pragma unroll
    for (int o = 1; o < 16; o <<= 1) {
      rs2[r] += __shfl_xor(rs2[r], o);
      rq2[r] += __shfl_xor(rq2[r], o);
    }
  }
  __syncthreads();  // lnS free (everyone past LN1 reads)
  if (lr == 0) {
#pragma unroll
    for (int r = 0; r < 4; r++) {
      lnS[(row4 + r) * 4 + w] = rs2[r];
      lnQ[(row4 + r) * 4 + w] = rq2[r];
    }
  }
  __syncthreads();
  {
    float mean[4], rsig[4];
#pragma unroll
    for (int r = 0; r < 4; r++) {
      int m = row4 + r;
      float s = lnS[m * 4] + lnS[m * 4 + 1] + lnS[m * 4 + 2] + lnS[m * 4 + 3];
      float q = lnQ[m * 4] + lnQ[m * 4 + 1] + lnQ[m * 4 + 2] + lnQ[m * 4 + 3];
      float mu = s * (1.f / 256.f);
      float va = q * (1.f / 256.f) - mu * mu;
      mean[r] = mu; rsig[r] = rsqrtf(va + 1e-5f);
    }
#pragma unroll
    for (int nt = 0; nt < 4; nt++) {
      int n = (w * 4 + nt) * 16 + lr;
      float g = g2[n], be = be2[n];
#pragma unroll
      for (int r = 0; r < 4; r++) {
        float y = (vals2[nt][r] - mean[r]) * rsig[r] * g + be;
        yout[(size_t)(m0 + row4 + r) * 256 + n] = y;
      }
    }
  }
}

// ---------------------------------------------------------------------------
extern "C" void kernel_launch(void* const* d_in, const int* in_sizes, int n_in,
                              void* d_out, int out_size, void* d_ws,
                              size_t ws_size, hipStream_t stream) {
  const float* x   = (const float*)d_in[0];
  const float* aw  = (const float*)d_in[1];
  const float* Wq  = (const float*)d_in[2];
  const float* bq  = (const float*)d_in[3];
  const float* Wk  = (const float*)d_in[4];
  const float* bk  = (const float*)d_in[5];
  const float* Wv  = (const float*)d_in[6];
  const float* bv  = (const float*)d_in[7];
  const float* Wo  = (const float*)d_in[8];
  const float* bo  = (const float*)d_in[9];
  const float* g1  = (const float*)d_in[10];
  const float* be1 = (const float*)d_in[11];
  const float* W1  = (const float*)d_in[12];
  const float* b1  = (const float*)d_in[13];
  const float* W2  = (const float*)d_in[14];
  const float* b2  = (const float*)d_in[15];
  const float* g2  = (const float*)d_in[16];
  const float* be2 = (const float*)d_in[17];

  if (ws_size < 34340864) return;  // scratch layout requirement

  char* ws = (char*)d_ws;
  ushort*   xb    = (ushort*)(ws + 0);          // 3,276,800
  ushort*   wqb   = (ushort*)(ws + 3276800);    //   131,072
  ushort*   wkb   = (ushort*)(ws + 3407872);
  ushort*   wvb   = (ushort*)(ws + 3538944);
  ushort*   wob   = (ushort*)(ws + 3670016);    //   131,072 (packed)
  ushort*   w1b   = (ushort*)(ws + 3801088);    //   524,288 (packed)
  ushort*   w2b   = (ushort*)(ws + 4325376);    //   524,288 (packed)
  _Float16* qhb   = (_Float16*)(ws + 4849664);  // 3,276,800  [b][h][m][32]*scl
  _Float16* khb   = (_Float16*)(ws + 8126464);  //            [b][h][m][32]
  _Float16* vtb   = (_Float16*)(ws + 11403264); //            [b][d][m]
  ushort*   attnb = (ushort*)(ws + 14680064);   // 3,276,800

  float* yout   = (float*)d_out;
  float* scores = yout + 1638400;

  convert_kernel<<<2368, 256, 0, stream>>>(x, Wq, Wk, Wv, Wo, W1, W2,
                                           xb, wqb, wkb, wvb, wob, w1b, w2b);
  qkv_gemm<<<dim3(4, 100, 3), 256, 0, stream>>>(
      xb, wqb, wkb, wvb, bq, bk, bv, qhb, khb, vtb);
  attn_kernel<<<3200, 256, 0, stream>>>(qhb, khb, vtb, aw, scores, attnb);
  tail_kernel<<<400, 256, 0, stream>>>(attnb, wob, bo, x, g1, be1,
                                       w1b, b1, w2b, b2, g2, be2, yout);
}